// Round 1
// baseline (11756.000 us; speedup 1.0000x reference)
//
#include <hip/hip_runtime.h>
#include <hip/hip_bf16.h>

typedef __attribute__((ext_vector_type(8))) short short8;
typedef __attribute__((ext_vector_type(4))) float f32x4;

#define HID 512
#define T_STEPS 90
#define RBLK 64
#define NBLK 256  /* 16384 rows / 64 */

__device__ inline unsigned short f2bf(float x) {
  unsigned int u = __float_as_uint(x);
  u = u + 0x7FFFu + ((u >> 16) & 1u);   // round-to-nearest-even
  return (unsigned short)(u >> 16);
}
__device__ inline float bf2f(unsigned short s) {
  return __uint_as_float(((unsigned int)s) << 16);
}

// ---- prep: fp32 weights -> bf16 in workspace ----
__global__ void prep_convert(const float* __restrict__ W1, const float* __restrict__ W2,
                             const float* __restrict__ Wout, unsigned short* __restrict__ wbf) {
  int i = blockIdx.x * blockDim.x + threadIdx.x;
  if (i >= 532480) return;
  float v;
  if (i < 262144) v = W1[i];
  else if (i < 524288) v = W2[i - 262144];
  else v = Wout[i - 524288];
  wbf[i] = f2bf(v);
}

// corr[t][o] = bout[o] - sum_h pos[t+1][h] * Woutbf[o][h]   (t<89; corr[89][o]=bout[o])
__global__ void prep_corr(const float* __restrict__ pos, const float* __restrict__ bout,
                          const unsigned short* __restrict__ Woutbf, float* __restrict__ corr) {
  int i = blockIdx.x * blockDim.x + threadIdx.x;
  if (i >= T_STEPS * 16) return;
  int t = i >> 4, o = i & 15;
  float s = 0.f;
  if (t < T_STEPS - 1) {
    const float* pe = pos + (t + 1) * HID;
    for (int h = 0; h < HID; ++h) s += pe[h] * bf2f(Woutbf[o * HID + h]);
  }
  corr[i] = bout[o] - s;
}

// one K=512 pass: acc[mt][nt] += A(lds rows cb-independent) * W^T, W is [512][512] bf16 row-major (B^T layout)
__device__ inline void gemm_tile(const unsigned short* lds,
                                 const unsigned short* __restrict__ Wbf,
                                 f32x4 (&acc)[4][4], int cb, int lh, int lq) {
  const unsigned short* wp0 = Wbf + (cb + 0 * 16 + lh) * HID + lq * 8;
  const unsigned short* wp1 = Wbf + (cb + 1 * 16 + lh) * HID + lq * 8;
  const unsigned short* wp2 = Wbf + (cb + 2 * 16 + lh) * HID + lq * 8;
  const unsigned short* wp3 = Wbf + (cb + 3 * 16 + lh) * HID + lq * 8;
  short8 bc[4], bn[4];
  bc[0] = *(const short8*)wp0; bc[1] = *(const short8*)wp1;
  bc[2] = *(const short8*)wp2; bc[3] = *(const short8*)wp3;
  const int abase = lh * HID + lq * 8;
  const int axor = (lh & 7) << 3;
#pragma unroll
  for (int kk = 0; kk < 16; ++kk) {
    if (kk < 15) {  // prefetch next B-frags (compile-time guard after unroll)
      bn[0] = *(const short8*)(wp0 + (kk + 1) * 32);
      bn[1] = *(const short8*)(wp1 + (kk + 1) * 32);
      bn[2] = *(const short8*)(wp2 + (kk + 1) * 32);
      bn[3] = *(const short8*)(wp3 + (kk + 1) * 32);
    }
    short8 af[4];
#pragma unroll
    for (int mt = 0; mt < 4; ++mt)
      af[mt] = *(const short8*)(lds + (((mt * 8192) + abase + kk * 32) ^ axor));
#pragma unroll
    for (int mt = 0; mt < 4; ++mt)
#pragma unroll
      for (int nt = 0; nt < 4; ++nt)
        acc[mt][nt] = __builtin_amdgcn_mfma_f32_16x16x32_bf16(af[mt], bc[nt], acc[mt][nt], 0, 0, 0);
    if (kk < 15) { bc[0] = bn[0]; bc[1] = bn[1]; bc[2] = bn[2]; bc[3] = bn[3]; }
  }
}

__global__ __launch_bounds__(512, 2) void fd_main(
    const float* __restrict__ latent, const float* __restrict__ b1,
    const float* __restrict__ b2, const float* __restrict__ pos,
    const unsigned short* __restrict__ W1bf, const unsigned short* __restrict__ W2bf,
    const unsigned short* __restrict__ Woutbf, const float* __restrict__ corr,
    float* __restrict__ out) {
  __shared__ __align__(16) unsigned short Xs[RBLK * HID];  // 64KB, X_t bf16 (swizzled)
  __shared__ __align__(16) unsigned short Hs[RBLK * HID];  // 64KB, h bf16 (swizzled)
  const int tid = threadIdx.x;
  const int w = tid >> 6;
  const int l = tid & 63;
  const int lh = l & 15, lq = l >> 4;
  const int cb = w << 6;        // this wave's 64-column slice
  const int cbl = cb + lh;
  const int rowBase = blockIdx.x * RBLK;

  float b1v[4], b2v[4];
#pragma unroll
  for (int nt = 0; nt < 4; ++nt) { b1v[nt] = b1[cbl + nt * 16]; b2v[nt] = b2[cbl + nt * 16]; }

  // state in registers, MFMA C-layout: st[mt][nt][r] = state[mt*16+lq*4+r][cb+nt*16+lh]
  f32x4 st[4][4];
#pragma unroll
  for (int mt = 0; mt < 4; ++mt)
#pragma unroll
    for (int nt = 0; nt < 4; ++nt) {
#pragma unroll
      for (int r = 0; r < 4; ++r)
        st[mt][nt][r] = latent[(size_t)(rowBase + mt * 16 + lq * 4 + r) * HID + cbl + nt * 16];
    }

  // write X_0 = state + pe[0]
  {
    float pev[4];
#pragma unroll
    for (int nt = 0; nt < 4; ++nt) pev[nt] = pos[cbl + nt * 16];
#pragma unroll
    for (int mt = 0; mt < 4; ++mt)
#pragma unroll
      for (int nt = 0; nt < 4; ++nt)
#pragma unroll
        for (int r = 0; r < 4; ++r) {
          int row = mt * 16 + lq * 4 + r;
          int idx = ((row << 9) + cbl + nt * 16) ^ ((row & 7) << 3);
          Xs[idx] = f2bf(st[mt][nt][r] + pev[nt]);
        }
  }
  __syncthreads();

  const unsigned short* woutp = Woutbf + lh * HID + lq * 8;

  for (int t = 0; t < T_STEPS; ++t) {
    // ---- GEMM1: a1 = X_t * W1^T + b1 ----
    f32x4 a1[4][4];
#pragma unroll
    for (int mt = 0; mt < 4; ++mt)
#pragma unroll
      for (int nt = 0; nt < 4; ++nt)
        a1[mt][nt] = (f32x4){b1v[nt], b1v[nt], b1v[nt], b1v[nt]};
    gemm_tile(Xs, W1bf, a1, cb, lh, lq);

    // ---- gelu (exact, erf) -> Hs ----
#pragma unroll
    for (int mt = 0; mt < 4; ++mt)
#pragma unroll
      for (int nt = 0; nt < 4; ++nt)
#pragma unroll
        for (int r = 0; r < 4; ++r) {
          float v = a1[mt][nt][r];
          float g = 0.5f * v * (1.0f + erff(v * 0.70710678118654752f));
          int row = mt * 16 + lq * 4 + r;
          int idx = ((row << 9) + cbl + nt * 16) ^ ((row & 7) << 3);
          Hs[idx] = f2bf(g);
        }
    __syncthreads();

    // ---- GEMM2: st = st + h * W2^T + b2  (residual accumulates in-place) ----
#pragma unroll
    for (int mt = 0; mt < 4; ++mt)
#pragma unroll
      for (int nt = 0; nt < 4; ++nt)
        st[mt][nt] += b2v[nt];
    gemm_tile(Hs, W2bf, st, cb, lh, lq);

    // ---- write X_{t+1} = state_t + pe[t+1]  (pe=0 for last step) ----
    {
      float pev[4] = {0.f, 0.f, 0.f, 0.f};
      if (t < T_STEPS - 1) {
#pragma unroll
        for (int nt = 0; nt < 4; ++nt) pev[nt] = pos[(t + 1) * HID + cbl + nt * 16];
      }
#pragma unroll
      for (int mt = 0; mt < 4; ++mt)
#pragma unroll
        for (int nt = 0; nt < 4; ++nt)
#pragma unroll
          for (int r = 0; r < 4; ++r) {
            int row = mt * 16 + lq * 4 + r;
            int idx = ((row << 9) + cbl + nt * 16) ^ ((row & 7) << 3);
            Xs[idx] = f2bf(st[mt][nt][r] + pev[nt]);
          }
    }
    __syncthreads();

    // ---- out-proj: out_t = X_{t+1} * Wout^T + corr[t]  (waves 0-3, one m-tile each) ----
    if (w < 4) {
      const int mt = w;
      float cv = corr[t * 16 + lh];
      f32x4 ao = {cv, cv, cv, cv};
      const int abase = lh * HID + lq * 8;
      const int axor = (lh & 7) << 3;
#pragma unroll
      for (int kk = 0; kk < 16; ++kk) {
        short8 af = *(const short8*)(Xs + (((mt * 8192) + abase + kk * 32) ^ axor));
        short8 bfr = *(const short8*)(woutp + kk * 32);
        ao = __builtin_amdgcn_mfma_f32_16x16x32_bf16(af, bfr, ao, 0, 0, 0);
      }
#pragma unroll
      for (int r = 0; r < 4; ++r) {
        int row = rowBase + mt * 16 + lq * 4 + r;
        int bb = row >> 8, ss = row & 255;
        out[(size_t)((bb * T_STEPS + t) * 256 + ss) * 16 + lh] = ao[r];
      }
    }
    // no barrier needed here: next write to Xs is after the next barrier;
    // out-GEMM reads complete before any wave passes it.
  }
}

extern "C" void kernel_launch(void* const* d_in, const int* in_sizes, int n_in,
                              void* d_out, int out_size, void* d_ws, size_t ws_size,
                              hipStream_t stream) {
  const float* latent = (const float*)d_in[0];
  const float* W1 = (const float*)d_in[1];
  const float* b1 = (const float*)d_in[2];
  const float* W2 = (const float*)d_in[3];
  const float* b2 = (const float*)d_in[4];
  const float* Wout = (const float*)d_in[5];
  const float* bout = (const float*)d_in[6];
  const float* pos = (const float*)d_in[7];

  unsigned short* wbf = (unsigned short*)d_ws;
  unsigned short* W1bf = wbf;                     // 512*512
  unsigned short* W2bf = wbf + 262144;            // 512*512
  unsigned short* Woutbf = wbf + 524288;          // 16*512
  float* corr = (float*)(wbf + 532480);           // byte off 1064960, 4-aligned; 90*16 floats

  prep_convert<<<2080, 256, 0, stream>>>(W1, W2, Wout, wbf);
  prep_corr<<<6, 256, 0, stream>>>(pos, bout, Woutbf, corr);
  fd_main<<<NBLK, 512, 0, stream>>>(latent, b1, b2, pos, W1bf, W2bf, Woutbf, corr,
                                    (float*)d_out);
}